// Round 9
// baseline (191.852 us; speedup 1.0000x reference)
//
#include <hip/hip_runtime.h>

// DYSPN — rolling-register SCATTER, barrier-free, LDS-free main kernel.
//
// out[b,h,w] = (G + att3)*cur/(S'+eps) + (1 - S_ppt/(S'+eps))*coarse
// with, for k = i*7+j (k != 24; CENTER_MASK kills the center tap):
//   S_ppt(h,w) = sum_k att[IDX[k]](h,w) * aff[k](h,w)      + att3
//   S'  (h,w)  = sum_k att[IDX[k]](h,w) * |aff[k]|(h,w)    + att3
//   G   (h,w)  = sum_k C_k(h+3-i, w+3-j),  C_k = att[IDX[k]] * aff[k]
//
// One WAVE per 4-row chunk: lane l holds cols 4l..4l+3 of the full 256-col
// row. For each of its 4 source rows the wave computes C at the source pixel
// (aff read EXACTLY once), folds the 7-j horizontal scatter with 6 shuffles
// per i (R7-verified), and adds the folded F into a statically-indexed
// register ring Acc[10] covering target rows y0-3..y0+6:
//   source row y0+s, tap-row i  ->  target row y0+s+i-3  ->  Acc[s+i].
// (R8 bug: used Acc[s+6-i] — vertical scatter inverted. R7's LDS version
// used lt = r+i-3; this is the same mapping in registers.)
// In-chunk targets finalize in registers; boundary targets go to a 6-row
// per-chunk global spill buffer applied by the small fix kernel
// (out += spill * scale, scale = cur/denom — R7-verified).

typedef float f32x4 __attribute__((ext_vector_type(4)));

constexpr int H = 256, W = 256, HW = H * W;
constexpr int P4 = HW / 4;    // plane stride in f32x4
constexpr int RW = W / 4;     // row stride in f32x4 (64)
constexpr int NR = 4;         // rows per chunk (one wave per chunk)
constexpr int NC = H / NR;    // 64 chunks per image
constexpr int NG = 16 * NC;   // 1024 chunks total

__global__ __launch_bounds__(64) void dyspn_main(
    const float* __restrict__ aff,    // [B,49,H,W]
    const float* __restrict__ attn,   // [B,4,H,W]
    const float* __restrict__ cur,    // [B,1,H,W]
    const float* __restrict__ coarse, // [B,1,H,W]
    float* __restrict__ out,          // [B,1,H,W]
    float* __restrict__ scale,        // [B,H,W]   (ws)
    float* __restrict__ spill)        // [NG][6][W] (ws): 0-2 up (targets y0-3..y0-1),
                                      //                  3-5 down (targets y0+4..y0+6)
{
    static constexpr int IDXR[7][7] = {
        {0,0,0,0,0,0,0},
        {0,1,1,1,1,1,0},
        {0,1,2,2,2,1,0},
        {0,1,2,3,2,1,0},
        {0,1,2,2,2,1,0},
        {0,1,1,1,1,1,0},
        {0,0,0,0,0,0,0}};

    const int c  = blockIdx.x;         // chunk id (1 wave per block)
    const int b  = c >> 6;             // image
    const int t  = c & 63;             // chunk within image
    const int y0 = t * NR;             // first target row
    const int w  = threadIdx.x;        // lane = col-group (4 cols)

    const f32x4* __restrict__ aff4 = (const f32x4*)aff  + (size_t)b * 49 * P4;
    const f32x4* __restrict__ att4 = (const f32x4*)attn + (size_t)b * 4  * P4;

    f32x4 Acc[10];                     // targets y0-3 .. y0+6 (idx = h-y0+3)
#pragma unroll
    for (int e = 0; e < 10; ++e) Acc[e] = f32x4{0.f, 0.f, 0.f, 0.f};
    f32x4 sp[NR], sa[NR];

#pragma unroll
    for (int s = 0; s < NR; ++s) {
        const int y = y0 + s;          // source row (always in-image)
        const int yrow = y * RW;

        f32x4 at_own[3];
        at_own[0] = att4[0 * P4 + yrow + w];
        at_own[1] = att4[1 * P4 + yrow + w];
        at_own[2] = att4[2 * P4 + yrow + w];

        f32x4 spv = {0.f,0.f,0.f,0.f}, sav = {0.f,0.f,0.f,0.f};

#pragma unroll
        for (int i = 0; i < 7; ++i) {
            // Hw[e] accumulates contributions to target col 4w-3+e, e in [0,10)
            float Hw[10];
#pragma unroll
            for (int e = 0; e < 10; ++e) Hw[e] = 0.f;

#pragma unroll
            for (int j = 0; j < 7; ++j) {
                if (i == 3 && j == 3) continue;      // center tap masked
                const int k = i * 7 + j;
                const int idx = IDXR[i][j];
                f32x4 a  = aff4[k * P4 + yrow + w];  // the single read of plane k
                f32x4 wt = at_own[idx];
#pragma unroll
                for (int cc = 0; cc < 4; ++cc) {
                    float C = wt[cc] * a[cc];
                    spv[cc] += C;                                   // S_ppt (own)
                    sav[cc]  = fmaf(wt[cc], fabsf(a[cc]), sav[cc]); // S' (own)
                    Hw[cc + j] += C;                                // horiz scatter
                }
            }

            // fold Hw across lanes (R7-verified): own col 4w+cc = Hw[cc+3]
            //  + left-neighbor Hw[cc+7] (cc<=2) + right-neighbor Hw[cc-1] (cc>=1)
            float L7 = __shfl(Hw[7], w - 1, 64);
            float L8 = __shfl(Hw[8], w - 1, 64);
            float L9 = __shfl(Hw[9], w - 1, 64);
            float R0 = __shfl(Hw[0], w + 1, 64);
            float R1 = __shfl(Hw[1], w + 1, 64);
            float R2 = __shfl(Hw[2], w + 1, 64);
            if (w == 0)  { L7 = 0.f; L8 = 0.f; L9 = 0.f; }
            if (w == 63) { R0 = 0.f; R1 = 0.f; R2 = 0.f; }
            f32x4 F;
            F[0] = Hw[3] + L7;
            F[1] = Hw[4] + L8 + R0;
            F[2] = Hw[5] + L9 + R1;
            F[3] = Hw[6] + R2;

            Acc[s + i] += F;           // target row y+i-3 -> Acc[(s+i-3)+3]

            // Bound load pipelining to one i-group (7 f32x4 = 28 VGPR):
            // without this the compiler hoists ~48 loads and spills (R6).
            __builtin_amdgcn_sched_barrier(0);
        }
        sp[s] = spv; sa[s] = sav;
    }

    // ---- epilogue: finalize the NR in-chunk target rows ----
    const f32x4* __restrict__ cur4 = (const f32x4*)cur    + (size_t)b * P4;
    const f32x4* __restrict__ cor4 = (const f32x4*)coarse + (size_t)b * P4;
    f32x4* __restrict__ out4       = (f32x4*)out          + (size_t)b * P4;
    f32x4* __restrict__ scl4       = (f32x4*)scale        + (size_t)b * P4;
#pragma unroll
    for (int s = 0; s < NR; ++s) {
        const int hrow = (y0 + s) * RW;
        f32x4 a3 = att4[3 * P4 + hrow + w];
        f32x4 cu = cur4[hrow + w];
        f32x4 co = cor4[hrow + w];
        f32x4 G  = Acc[s + 3];
        f32x4 o, sc;
#pragma unroll
        for (int cc = 0; cc < 4; ++cc) {
            float s_pr  = sa[s][cc] + a3[cc];
            float s_ppt = sp[s][cc] + a3[cc];
            float inv = 1.0f / (s_pr + 1e-6f);
            sc[cc] = cu[cc] * inv;
            o[cc]  = (G[cc] + a3[cc]) * sc[cc] + (1.f - s_ppt * inv) * co[cc];
        }
        out4[hrow + w] = o;
        scl4[hrow + w] = sc;
    }

    // ---- export boundary targets (always fully written) ----
    f32x4* __restrict__ sp4 = (f32x4*)(spill + (size_t)c * 6 * W);
#pragma unroll
    for (int rr = 0; rr < 3; ++rr) {
        sp4[rr * RW + w]       = Acc[rr];      // up:   targets y0-3+rr
        sp4[(3 + rr) * RW + w] = Acc[7 + rr];  // down: targets y0+4+rr
    }
}

// Apply cross-chunk spill (R7-verified). Chunk t (rows [4t, 4t+4)):
//   local rows 0..2 += chunk(t-1).down[0..2]   (targets y0..y0+2)
//   local rows 1..3 += chunk(t+1).up[0..2]     (targets y0+1..y0+3)
__global__ __launch_bounds__(256) void dyspn_fix(
    float* __restrict__ out, const float* __restrict__ scale,
    const float* __restrict__ spill)
{
    const int g = blockIdx.x;
    const int b = g >> 6, t = g & 63;
    const int col = threadIdx.x;
    const size_t obase = (size_t)b * HW;

    if (t > 0) {
#pragma unroll
        for (int row = 0; row < 3; ++row) {
            float v = spill[(size_t)(g - 1) * 6 * W + (3 + row) * W + col];
            int p = (t * NR + row) * W + col;
            out[obase + p] += v * scale[obase + p];
        }
    }
    if (t < NC - 1) {
#pragma unroll
        for (int row = 0; row < 3; ++row) {
            float v = spill[(size_t)(g + 1) * 6 * W + row * W + col];
            int p = (t * NR + 1 + row) * W + col;
            out[obase + p] += v * scale[obase + p];
        }
    }
}

extern "C" void kernel_launch(void* const* d_in, const int* in_sizes, int n_in,
                              void* d_out, int out_size, void* d_ws, size_t ws_size,
                              hipStream_t stream) {
    const float* aff    = (const float*)d_in[0];
    const float* attn   = (const float*)d_in[1];
    const float* cur    = (const float*)d_in[2];
    const float* coarse = (const float*)d_in[3];
    float* out = (float*)d_out;

    float* scale = (float*)d_ws;                 // 16*HW floats = 4 MiB
    float* spill = scale + (size_t)16 * HW;      // NG*6*W floats = 6 MiB

    hipLaunchKernelGGL(dyspn_main, dim3(NG), dim3(64), 0, stream,
                       aff, attn, cur, coarse, out, scale, spill);
    hipLaunchKernelGGL(dyspn_fix, dim3(NG), dim3(256), 0, stream,
                       out, scale, spill);
}